// Round 1
// 678.667 us; speedup vs baseline: 2.8095x; 2.8095x over previous
//
#include <hip/hip_runtime.h>
#include <stdint.h>

constexpr int kB = 8;
constexpr int kN = 128;
constexpr int kC = 256;
#define ATTN_SCALE 0.0625f

using half8 = __attribute__((ext_vector_type(8))) _Float16;
using half4 = __attribute__((ext_vector_type(4))) _Float16;
using f32x4 = __attribute__((ext_vector_type(4))) float;

// ---------------------------------------------------------------------------
// Kernel 1: q = mol@Wq+bq (f32), k = prot@Wk+bk (f16), v = mol@Wv+bv (f32)
// ---------------------------------------------------------------------------
__global__ __launch_bounds__(256) void qkv_kernel(
    const float* __restrict__ mol_annot,
    const float* __restrict__ prot_annot,
    const float* __restrict__ Wq, const float* __restrict__ bq,
    const float* __restrict__ Wk, const float* __restrict__ bk,
    const float* __restrict__ Wv, const float* __restrict__ bv,
    float* __restrict__ qf, _Float16* __restrict__ kf16, float* __restrict__ vf)
{
    const int row = blockIdx.x;
    const int t   = threadIdx.x;

    __shared__ float sm[kC];
    __shared__ float sp[kC];
    sm[t] = mol_annot[row * kC + t];
    sp[t] = prot_annot[row * kC + t];
    __syncthreads();

    float aq = bq[t];
    float ak = bk[t];
    float av = bv[t];
    for (int c = 0; c < kC; ++c) {
        const float m = sm[c];
        const float p = sp[c];
        aq += m * Wq[c * kC + t];
        ak += p * Wk[c * kC + t];
        av += m * Wv[c * kC + t];
    }
    qf[row * kC + t]   = aq;
    kf16[row * kC + t] = (_Float16)ak;
    vf[row * kC + t]   = av;
}

// ---------------------------------------------------------------------------
// Kernel 2: pack Wva/Wka/Woed (f32 row-major [K=256][N=256]) into
// fragment-linear f16: dst[((nblk*8 + kblk)*64 + lane)*8 + i]
// where B-frag element = B[k = kblk*32 + (lane>>4)*8 + i][n = nblk*16 + (lane&15)]
// ---------------------------------------------------------------------------
__global__ __launch_bounds__(256) void pack_w_kernel(
    const float* __restrict__ Wva, const float* __restrict__ Wka,
    const float* __restrict__ Woed,
    _Float16* __restrict__ p_wva, _Float16* __restrict__ p_wka,
    _Float16* __restrict__ p_woed)
{
    const int blk = blockIdx.x;            // mat*256 + k
    const int mat = blk >> 8;
    const int k   = blk & 255;
    const int n   = threadIdx.x;

    const float* src = (mat == 0) ? Wva : (mat == 1) ? Wka : Woed;
    _Float16*    dst = (mat == 0) ? p_wva : (mat == 1) ? p_wka : p_woed;

    const float w   = src[k * kC + n];
    const int nblk  = n >> 4;
    const int kblk  = k >> 5;
    const int lane  = (((k >> 3) & 3) << 4) | (n & 15);
    const int i     = k & 7;
    dst[(size_t)(((nblk * 8) + kblk) * 64 + lane) * 8 + i] = (_Float16)w;
}

// ---------------------------------------------------------------------------
// Kernel 3: per (b,m): me/pe MFMA GEMMs -> gate -> Woed MFMA GEMM + softmax
// 512 threads = 8 waves as 2(M) x 4(N); wave tile 64 rows x 64 cols.
// ---------------------------------------------------------------------------
__global__ __launch_bounds__(512, 2) void main_kernel(
    const float* __restrict__ mol_adj,
    const float* __restrict__ prot_adj,
    const float* __restrict__ bka, const float* __restrict__ bva,
    const float* __restrict__ Wond, const float* __restrict__ bond,
    const float* __restrict__ boed,
    const _Float16* __restrict__ p_wva, const _Float16* __restrict__ p_wka,
    const _Float16* __restrict__ p_woed,
    const float* __restrict__ qf, const _Float16* __restrict__ kf16,
    const float* __restrict__ vf,
    float* __restrict__ out_node,   // [B,N,C]
    float* __restrict__ out_edge)   // [B,N,N,C]
{
    const int bm   = blockIdx.x;      // b*N + m
    const int b    = bm >> 7;
    const int tid  = threadIdx.x;
    const int lane = tid & 63;
    const int wave = tid >> 6;
    const int wm   = wave >> 2;       // 0..1  (M half: rows wm*64..)
    const int wn   = wave & 3;        // 0..3  (N quarter: cols wn*64..)
    const int lr   = lane & 15;       // row within 16x16 tile (A) / col (B, C/D)
    const int lk   = (lane >> 4) << 3; // k offset 0,8,16,24
    const int lg4  = (lane >> 4) << 2; // C/D row base 0,4,8,12

    // LDS: stage buffer (2 matrices x 128 rows x 128 k, padded to 136) aliased
    // with attn (128 x 256, padded to 264). 69632 B.
    __shared__ __align__(16) _Float16 s_stage[2][kN][136];
    _Float16 (*s_attn)[264] = reinterpret_cast<_Float16 (*)[264]>(&s_stage[0][0][0]);
    __shared__ float s_red[6][kC];
    __shared__ float s_node[kC];

    // per-lane column constants (4 N-frags)
    float qs[4], bva_c[4], bka_c[4], boed_c[4];
    int   colv[4];
    #pragma unroll
    for (int ni = 0; ni < 4; ++ni) {
        const int c = wn * 64 + ni * 16 + lr;
        colv[ni]   = c;
        qs[ni]     = qf[(size_t)bm * kC + c] * ATTN_SCALE;
        bva_c[ni]  = bva[c];
        bka_c[ni]  = bka[c];
        boed_c[ni] = boed[c];
    }

    const float* madj = mol_adj  + (size_t)bm * kN * kC;
    const float* padj = prot_adj + (size_t)bm * kN * kC;

    // ---- Phase 1: me = mol_adj@Wva, pe = prot_adj@Wka (K chunked by 128)
    f32x4 accme[4][4], accpe[4][4];
    #pragma unroll
    for (int mi = 0; mi < 4; ++mi)
        #pragma unroll
        for (int ni = 0; ni < 4; ++ni) { accme[mi][ni] = (f32x4)0.0f; accpe[mi][ni] = (f32x4)0.0f; }

    for (int kc = 0; kc < 2; ++kc) {
        // stage f32 -> f16 into LDS (both matrices), coalesced float4 loads
        #pragma unroll
        for (int v = 0; v < 8; ++v) {
            const int e   = tid + v * 512;    // 0..4095 float4 units
            const int row = e >> 5;           // 32 float4 per row-chunk
            const int c4  = e & 31;
            const float4 fm = *(const float4*)(madj + row * kC + kc * 128 + c4 * 4);
            const float4 fp = *(const float4*)(padj + row * kC + kc * 128 + c4 * 4);
            half4 hm, hp;
            hm[0] = (_Float16)fm.x; hm[1] = (_Float16)fm.y;
            hm[2] = (_Float16)fm.z; hm[3] = (_Float16)fm.w;
            hp[0] = (_Float16)fp.x; hp[1] = (_Float16)fp.y;
            hp[2] = (_Float16)fp.z; hp[3] = (_Float16)fp.w;
            *(half4*)&s_stage[0][row][c4 * 4] = hm;
            *(half4*)&s_stage[1][row][c4 * 4] = hp;
        }
        __syncthreads();

        #pragma unroll
        for (int kk = 0; kk < 4; ++kk) {
            const int kblk = kc * 4 + kk;
            half8 am[4], ap[4], bvf[4], bkf[4];
            #pragma unroll
            for (int mi = 0; mi < 4; ++mi) {
                const int r = wm * 64 + mi * 16 + lr;
                am[mi] = *(const half8*)&s_stage[0][r][kk * 32 + lk];
                ap[mi] = *(const half8*)&s_stage[1][r][kk * 32 + lk];
            }
            #pragma unroll
            for (int ni = 0; ni < 4; ++ni) {
                const size_t off = ((size_t)((wn * 4 + ni) * 8 + kblk) * 64 + lane) * 8;
                bvf[ni] = *(const half8*)&p_wva[off];
                bkf[ni] = *(const half8*)&p_wka[off];
            }
            #pragma unroll
            for (int mi = 0; mi < 4; ++mi)
                #pragma unroll
                for (int ni = 0; ni < 4; ++ni) {
                    accme[mi][ni] = __builtin_amdgcn_mfma_f32_16x16x32_f16(am[mi], bvf[ni], accme[mi][ni], 0, 0, 0);
                    accpe[mi][ni] = __builtin_amdgcn_mfma_f32_16x16x32_f16(ap[mi], bkf[ni], accpe[mi][ni], 0, 0, 0);
                }
        }
        __syncthreads();   // stage buffer reads done before rewrite
    }

    // ---- Gate: attn = q*k*scale*(pe+1)*me ; write f16 attn tile to LDS
    const _Float16* kbase = kf16 + (size_t)b * kN * kC;
    #pragma unroll
    for (int mi = 0; mi < 4; ++mi) {
        #pragma unroll
        for (int ni = 0; ni < 4; ++ni) {
            #pragma unroll
            for (int r = 0; r < 4; ++r) {
                const int row = wm * 64 + mi * 16 + lg4 + r;
                const float kvv = (float)kbase[row * kC + colv[ni]];
                const float me  = accme[mi][ni][r] + bva_c[ni];
                const float pe  = accpe[mi][ni][r] + bka_c[ni];
                const float a   = qs[ni] * kvv * (pe + 1.0f) * me;
                s_attn[row][colv[ni]] = (_Float16)a;
            }
        }
    }
    __syncthreads();

    // ---- Phase 2: oed = attn @ Woed + boed (MFMA from LDS attn)
    f32x4 acco[4][4];
    #pragma unroll
    for (int mi = 0; mi < 4; ++mi)
        #pragma unroll
        for (int ni = 0; ni < 4; ++ni) acco[mi][ni] = (f32x4)0.0f;

    #pragma unroll
    for (int kk = 0; kk < 8; ++kk) {
        half8 aa[4], bo[4];
        #pragma unroll
        for (int mi = 0; mi < 4; ++mi)
            aa[mi] = *(const half8*)&s_attn[wm * 64 + mi * 16 + lr][kk * 32 + lk];
        #pragma unroll
        for (int ni = 0; ni < 4; ++ni)
            bo[ni] = *(const half8*)&p_woed[((size_t)((wn * 4 + ni) * 8 + kk) * 64 + lane) * 8];
        #pragma unroll
        for (int mi = 0; mi < 4; ++mi)
            #pragma unroll
            for (int ni = 0; ni < 4; ++ni)
                acco[mi][ni] = __builtin_amdgcn_mfma_f32_16x16x32_f16(aa[mi], bo[ni], acco[mi][ni], 0, 0, 0);
    }

    float* oe = out_edge + (size_t)bm * kN * kC;
    #pragma unroll
    for (int mi = 0; mi < 4; ++mi)
        #pragma unroll
        for (int ni = 0; ni < 4; ++ni)
            #pragma unroll
            for (int r = 0; r < 4; ++r) {
                const int row = wm * 64 + mi * 16 + lg4 + r;
                oe[(size_t)row * kC + colv[ni]] = acco[mi][ni][r] + boed_c[ni];
            }

    // ---- Softmax over n (rows) per column c, split rows across 2 thread halves
    {
        const int c  = tid & 255;
        const int hh = tid >> 8;        // 0/1: rows 0..63 / 64..127
        const int r0 = hh * 64;

        float mx = -1.0e30f;
        #pragma unroll 4
        for (int r = 0; r < 64; ++r) mx = fmaxf(mx, (float)s_attn[r0 + r][c]);
        s_red[hh][c] = mx;
        __syncthreads();
        mx = fmaxf(s_red[0][c], s_red[1][c]);

        const float* vbase = vf + (size_t)b * kN * kC;
        float ssum = 0.0f, sacc = 0.0f;
        #pragma unroll 4
        for (int r = 0; r < 64; ++r) {
            const float a = (float)s_attn[r0 + r][c];
            const float e = __expf(a - mx);
            ssum += e;
            sacc += e * vbase[(size_t)(r0 + r) * kC + c];
        }
        s_red[2 + hh][c] = ssum;
        s_red[4 + hh][c] = sacc;
        __syncthreads();
        if (tid < 256) {
            s_node[tid] = (s_red[4][tid] + s_red[5][tid]) /
                          (s_red[2][tid] + s_red[3][tid]);
        }
        __syncthreads();
    }

    // ---- node @ Wond + bond
    if (tid < 256) {
        float acc = bond[tid];
        const float4* sn4 = reinterpret_cast<const float4*>(s_node);
        for (int c4 = 0; c4 < 64; ++c4) {
            const float4 nv = sn4[c4];
            acc += nv.x * Wond[(c4 * 4 + 0) * kC + tid];
            acc += nv.y * Wond[(c4 * 4 + 1) * kC + tid];
            acc += nv.z * Wond[(c4 * 4 + 2) * kC + tid];
            acc += nv.w * Wond[(c4 * 4 + 3) * kC + tid];
        }
        out_node[(size_t)bm * kC + tid] = acc;
    }
}

// ---------------------------------------------------------------------------
extern "C" void kernel_launch(void* const* d_in, const int* in_sizes, int n_in,
                              void* d_out, int out_size, void* d_ws, size_t ws_size,
                              hipStream_t stream)
{
    const float* mol_annot  = (const float*)d_in[0];
    const float* prot_annot = (const float*)d_in[1];
    const float* mol_adj    = (const float*)d_in[2];
    const float* prot_adj   = (const float*)d_in[3];
    const float* Wq  = (const float*)d_in[4];
    const float* bq  = (const float*)d_in[5];
    const float* Wk  = (const float*)d_in[6];
    const float* bk  = (const float*)d_in[7];
    const float* Wv  = (const float*)d_in[8];
    const float* bv  = (const float*)d_in[9];
    const float* Wka = (const float*)d_in[10];
    const float* bka = (const float*)d_in[11];
    const float* Wva = (const float*)d_in[12];
    const float* bva = (const float*)d_in[13];
    const float* Wond = (const float*)d_in[14];
    const float* bond = (const float*)d_in[15];
    const float* Woed = (const float*)d_in[16];
    const float* boed = (const float*)d_in[17];

    // workspace layout (2.875 MB total, fits the 3 MB previously used):
    //   qf   f32 [B,N,C]  1 MB
    //   vf   f32 [B,N,C]  1 MB
    //   kf16 f16 [B,N,C]  0.5 MB
    //   p_wva/p_wka/p_woed f16 packed [256*256] each, 128 KB each
    float*    qf    = (float*)d_ws;
    float*    vf    = qf + (size_t)kB * kN * kC;
    _Float16* kf16  = (_Float16*)(vf + (size_t)kB * kN * kC);
    _Float16* p_wva = kf16 + (size_t)kB * kN * kC;
    _Float16* p_wka = p_wva + (size_t)kC * kC;
    _Float16* p_woed = p_wka + (size_t)kC * kC;

    float* out  = (float*)d_out;
    float* out0 = out;
    float* out1 = out + (size_t)kB * kN * kC;
    float* out2 = out + (size_t)2 * kB * kN * kC;
    float* out3 = out2 + (size_t)kB * kN * kN * kC;

    // passthroughs
    hipMemcpyAsync(out1, prot_annot, (size_t)kB * kN * kC * sizeof(float),
                   hipMemcpyDeviceToDevice, stream);
    hipMemcpyAsync(out3, prot_adj, (size_t)kB * kN * kN * kC * sizeof(float),
                   hipMemcpyDeviceToDevice, stream);

    qkv_kernel<<<dim3(kB * kN), dim3(256), 0, stream>>>(
        mol_annot, prot_annot, Wq, bq, Wk, bk, Wv, bv, qf, kf16, vf);

    pack_w_kernel<<<dim3(3 * kC), dim3(256), 0, stream>>>(
        Wva, Wka, Woed, p_wva, p_wka, p_woed);

    main_kernel<<<dim3(kB * kN), dim3(512), 0, stream>>>(
        mol_adj, prot_adj, bka, bva, Wond, bond, boed,
        p_wva, p_wka, p_woed, qf, kf16, vf, out0, out2);
}

// Round 2
// 611.237 us; speedup vs baseline: 3.1194x; 1.1103x over previous
//
#include <hip/hip_runtime.h>
#include <stdint.h>

constexpr int kB = 8;
constexpr int kN = 128;
constexpr int kC = 256;
#define ATTN_SCALE 0.0625f

using half8 = __attribute__((ext_vector_type(8))) _Float16;
using half4 = __attribute__((ext_vector_type(4))) _Float16;
using f32x4 = __attribute__((ext_vector_type(4))) float;

// ---------------------------------------------------------------------------
// Kernel 1: q = mol@Wq+bq (f32), k = prot@Wk+bk (f16), v = mol@Wv+bv (f32)
// Also folds the prot_annot passthrough (out1).
// ---------------------------------------------------------------------------
__global__ __launch_bounds__(256) void qkv_kernel(
    const float* __restrict__ mol_annot,
    const float* __restrict__ prot_annot,
    const float* __restrict__ Wq, const float* __restrict__ bq,
    const float* __restrict__ Wk, const float* __restrict__ bk,
    const float* __restrict__ Wv, const float* __restrict__ bv,
    float* __restrict__ qf, _Float16* __restrict__ kf16, float* __restrict__ vf,
    float* __restrict__ out1)
{
    const int row = blockIdx.x;
    const int t   = threadIdx.x;

    __shared__ float sm[kC];
    __shared__ float sp[kC];
    const float pv = prot_annot[row * kC + t];
    sm[t] = mol_annot[row * kC + t];
    sp[t] = pv;
    out1[row * kC + t] = pv;          // passthrough fold
    __syncthreads();

    float aq = bq[t];
    float ak = bk[t];
    float av = bv[t];
    for (int c = 0; c < kC; ++c) {
        const float m = sm[c];
        const float p = sp[c];
        aq += m * Wq[c * kC + t];
        ak += p * Wk[c * kC + t];
        av += m * Wv[c * kC + t];
    }
    qf[row * kC + t]   = aq;
    kf16[row * kC + t] = (_Float16)ak;
    vf[row * kC + t]   = av;
}

// ---------------------------------------------------------------------------
// Kernel 2: pack Wva/Wka/Woed (f32 row-major [K=256][N=256]) into
// fragment-linear f16: dst[((nblk*8 + kblk)*64 + lane)*8 + i]
// B-frag element = B[k = kblk*32 + (lane>>4)*8 + i][n = nblk*16 + (lane&15)]
// ---------------------------------------------------------------------------
__global__ __launch_bounds__(256) void pack_w_kernel(
    const float* __restrict__ Wva, const float* __restrict__ Wka,
    const float* __restrict__ Woed,
    _Float16* __restrict__ p_wva, _Float16* __restrict__ p_wka,
    _Float16* __restrict__ p_woed)
{
    const int blk = blockIdx.x;
    const int mat = blk >> 8;
    const int k   = blk & 255;
    const int n   = threadIdx.x;

    const float* src = (mat == 0) ? Wva : (mat == 1) ? Wka : Woed;
    _Float16*    dst = (mat == 0) ? p_wva : (mat == 1) ? p_wka : p_woed;

    const float w   = src[k * kC + n];
    const int nblk  = n >> 4;
    const int kblk  = k >> 5;
    const int lane  = (((k >> 3) & 3) << 4) | (n & 15);
    const int i     = k & 7;
    dst[(size_t)(((nblk * 8) + kblk) * 64 + lane) * 8 + i] = (_Float16)w;
}

// ---------------------------------------------------------------------------
// Kernel 3: per (b,m). Sequential GEMMs sharing one 64-reg accumulator:
//   A: pe = prot_adj@Wka  -> (pe+1) f16 stashed in s_attn (+ out3 passthrough)
//   B: me = mol_adj@Wva   -> gate in place -> attn f16 in s_attn
//   2: oed = attn@Woed    -> softmax -> LDS-restaged coalesced stores
// 512 threads = 8 waves (2M x 4N), wave tile 64x64. 2 blocks/CU target.
// ---------------------------------------------------------------------------
__global__ __launch_bounds__(512, 4) void main_kernel(
    const float* __restrict__ mol_adj,
    const float* __restrict__ prot_adj,
    const float* __restrict__ bka, const float* __restrict__ bva,
    const float* __restrict__ Wond, const float* __restrict__ bond,
    const float* __restrict__ boed,
    const _Float16* __restrict__ p_wva, const _Float16* __restrict__ p_wka,
    const _Float16* __restrict__ p_woed,
    const float* __restrict__ qf, const _Float16* __restrict__ kf16,
    const float* __restrict__ vf,
    float* __restrict__ out_node,   // [B,N,C]
    float* __restrict__ out_edge,   // [B,N,N,C]
    float* __restrict__ out3)       // prot_adj passthrough
{
    const int bm   = blockIdx.x;
    const int b    = bm >> 7;
    const int tid  = threadIdx.x;
    const int lane = tid & 63;
    const int wave = tid >> 6;
    const int wm   = wave >> 2;
    const int wn   = wave & 3;
    const int lr   = lane & 15;
    const int lk   = (lane >> 4) << 3;
    const int lg4  = (lane >> 4) << 2;

    __shared__ __align__(16) _Float16 s_attn[kN][264];   // 67584 B: ppe -> attn
    __shared__ __align__(16) _Float16 s_stage[kN][40];   // 10240 B: K=32 stage
    float (*s_red)[kC] = reinterpret_cast<float (*)[kC]>(&s_stage[0][0]); // [7][256] alias
    float (*s_oe)[260] = reinterpret_cast<float (*)[260]>(&s_attn[0][0]); // 64x260 f32 alias

    const float* madj = mol_adj  + (size_t)bm * kN * kC;
    const float* padj = prot_adj + (size_t)bm * kN * kC;
    float*       o3   = out3     + (size_t)bm * kN * kC;

    const int srow = tid >> 3;         // 0..63
    const int sc4  = (tid & 7) * 4;    // 0,4,...,28

    f32x4 acc[4][4];

    // ================= Phase A: pe = prot_adj @ Wka =================
    #pragma unroll
    for (int mi = 0; mi < 4; ++mi)
        #pragma unroll
        for (int ni = 0; ni < 4; ++ni) acc[mi][ni] = (f32x4)0.0f;

    for (int kc = 0; kc < 8; ++kc) {
        #pragma unroll
        for (int v = 0; v < 2; ++v) {
            const int r = srow + v * 64;
            const float4 f = *(const float4*)(padj + r * kC + kc * 32 + sc4);
            *(float4*)(o3 + r * kC + kc * 32 + sc4) = f;   // passthrough fold
            half4 h;
            h[0] = (_Float16)f.x; h[1] = (_Float16)f.y;
            h[2] = (_Float16)f.z; h[3] = (_Float16)f.w;
            *(half4*)&s_stage[r][sc4] = h;
        }
        __syncthreads();

        half8 af[4];
        #pragma unroll
        for (int mi = 0; mi < 4; ++mi)
            af[mi] = *(const half8*)&s_stage[wm * 64 + mi * 16 + lr][lk];
        #pragma unroll
        for (int ni = 0; ni < 4; ++ni) {
            const half8 bf = *(const half8*)&p_wka[((size_t)((wn * 4 + ni) * 8 + kc) * 64 + lane) * 8];
            #pragma unroll
            for (int mi = 0; mi < 4; ++mi)
                acc[mi][ni] = __builtin_amdgcn_mfma_f32_16x16x32_f16(af[mi], bf, acc[mi][ni], 0, 0, 0);
        }
        __syncthreads();
    }

    // stash ppe = pe + 1 (f16, own slots)
    #pragma unroll
    for (int ni = 0; ni < 4; ++ni) {
        const int col = wn * 64 + ni * 16 + lr;
        const float bk_c = bka[col] + 1.0f;
        #pragma unroll
        for (int mi = 0; mi < 4; ++mi)
            #pragma unroll
            for (int r = 0; r < 4; ++r)
                s_attn[wm * 64 + mi * 16 + lg4 + r][col] = (_Float16)(acc[mi][ni][r] + bk_c);
    }

    // ================= Phase B: me = mol_adj @ Wva =================
    #pragma unroll
    for (int mi = 0; mi < 4; ++mi)
        #pragma unroll
        for (int ni = 0; ni < 4; ++ni) acc[mi][ni] = (f32x4)0.0f;

    for (int kc = 0; kc < 8; ++kc) {
        #pragma unroll
        for (int v = 0; v < 2; ++v) {
            const int r = srow + v * 64;
            const float4 f = *(const float4*)(madj + r * kC + kc * 32 + sc4);
            half4 h;
            h[0] = (_Float16)f.x; h[1] = (_Float16)f.y;
            h[2] = (_Float16)f.z; h[3] = (_Float16)f.w;
            *(half4*)&s_stage[r][sc4] = h;
        }
        __syncthreads();

        half8 af[4];
        #pragma unroll
        for (int mi = 0; mi < 4; ++mi)
            af[mi] = *(const half8*)&s_stage[wm * 64 + mi * 16 + lr][lk];
        #pragma unroll
        for (int ni = 0; ni < 4; ++ni) {
            const half8 bf = *(const half8*)&p_wva[((size_t)((wn * 4 + ni) * 8 + kc) * 64 + lane) * 8];
            #pragma unroll
            for (int mi = 0; mi < 4; ++mi)
                acc[mi][ni] = __builtin_amdgcn_mfma_f32_16x16x32_f16(af[mi], bf, acc[mi][ni], 0, 0, 0);
        }
        __syncthreads();
    }

    // gate in place: attn = q*k*scale * ppe * me  (own slots, no barrier needed)
    {
        const _Float16* kb  = kf16 + (size_t)b * kN * kC;
        const float*   qrow = qf   + (size_t)bm * kC;
        #pragma unroll
        for (int ni = 0; ni < 4; ++ni) {
            const int col = wn * 64 + ni * 16 + lr;
            const float qs   = qrow[col] * ATTN_SCALE;
            const float bv_c = bva[col];
            #pragma unroll
            for (int mi = 0; mi < 4; ++mi)
                #pragma unroll
                for (int r = 0; r < 4; ++r) {
                    const int row = wm * 64 + mi * 16 + lg4 + r;
                    const float kvv = (float)kb[row * kC + col];
                    const float ppe = (float)s_attn[row][col];
                    const float me  = acc[mi][ni][r] + bv_c;
                    s_attn[row][col] = (_Float16)(qs * kvv * ppe * me);
                }
        }
    }
    __syncthreads();

    // ================= Phase 2: oed = attn @ Woed =================
    #pragma unroll
    for (int mi = 0; mi < 4; ++mi)
        #pragma unroll
        for (int ni = 0; ni < 4; ++ni) acc[mi][ni] = (f32x4)0.0f;

    #pragma unroll
    for (int kk = 0; kk < 8; ++kk) {
        half8 aa[4];
        #pragma unroll
        for (int mi = 0; mi < 4; ++mi)
            aa[mi] = *(const half8*)&s_attn[wm * 64 + mi * 16 + lr][kk * 32 + lk];
        #pragma unroll
        for (int ni = 0; ni < 4; ++ni) {
            const half8 bo = *(const half8*)&p_woed[((size_t)((wn * 4 + ni) * 8 + kk) * 64 + lane) * 8];
            #pragma unroll
            for (int mi = 0; mi < 4; ++mi)
                acc[mi][ni] = __builtin_amdgcn_mfma_f32_16x16x32_f16(aa[mi], bo, acc[mi][ni], 0, 0, 0);
        }
    }

    // ================= Softmax over n (rows) per column =================
    {
        const int c  = tid & 255;
        const int hh = tid >> 8;
        const int r0 = hh * 64;

        float mx = -1.0e30f;
        #pragma unroll 4
        for (int r = 0; r < 64; ++r) mx = fmaxf(mx, (float)s_attn[r0 + r][c]);
        s_red[hh][c] = mx;
        __syncthreads();
        mx = fmaxf(s_red[0][c], s_red[1][c]);

        const float* vb = vf + (size_t)b * kN * kC;
        float ssum = 0.0f, sacc = 0.0f;
        #pragma unroll 4
        for (int r = 0; r < 64; ++r) {
            const float a = (float)s_attn[r0 + r][c];
            const float e = __expf(a - mx);
            ssum += e;
            sacc += e * vb[(size_t)(r0 + r) * kC + c];
        }
        s_red[2 + hh][c] = ssum;
        s_red[4 + hh][c] = sacc;
        __syncthreads();
        if (tid < 256) {
            s_red[6][tid] = (s_red[4][tid] + s_red[5][tid]) /
                            (s_red[2][tid] + s_red[3][tid]);
        }
    }
    __syncthreads();   // all s_attn reads (phase 2 + softmax) complete

    // ========== epilogue: restage acco through LDS, coalesced stores ==========
    {
        float* oe = out_edge + (size_t)bm * kN * kC;
        #pragma unroll
        for (int h = 0; h < 2; ++h) {
            if (wm == h) {
                #pragma unroll
                for (int ni = 0; ni < 4; ++ni) {
                    const int col = wn * 64 + ni * 16 + lr;
                    const float bo_c = boed[col];
                    #pragma unroll
                    for (int mi = 0; mi < 4; ++mi)
                        #pragma unroll
                        for (int r = 0; r < 4; ++r)
                            s_oe[mi * 16 + lg4 + r][col] = acc[mi][ni][r] + bo_c;
                }
            }
            __syncthreads();
            #pragma unroll
            for (int v = 0; v < 8; ++v) {
                const int e   = v * 512 + tid;
                const int row = e >> 6;
                const int c4  = (e & 63) * 4;
                const float4 val = *(const float4*)&s_oe[row][c4];
                *(float4*)(oe + (size_t)(h * 64 + row) * kC + c4) = val;
            }
            __syncthreads();
        }
    }

    // ================= node @ Wond + bond =================
    if (tid < 256) {
        float accn = bond[tid];
        const float4* sn4 = reinterpret_cast<const float4*>(&s_red[6][0]);
        for (int c4 = 0; c4 < 64; ++c4) {
            const float4 nv = sn4[c4];
            accn += nv.x * Wond[(c4 * 4 + 0) * kC + tid];
            accn += nv.y * Wond[(c4 * 4 + 1) * kC + tid];
            accn += nv.z * Wond[(c4 * 4 + 2) * kC + tid];
            accn += nv.w * Wond[(c4 * 4 + 3) * kC + tid];
        }
        out_node[(size_t)bm * kC + tid] = accn;
    }
}

// ---------------------------------------------------------------------------
extern "C" void kernel_launch(void* const* d_in, const int* in_sizes, int n_in,
                              void* d_out, int out_size, void* d_ws, size_t ws_size,
                              hipStream_t stream)
{
    const float* mol_annot  = (const float*)d_in[0];
    const float* prot_annot = (const float*)d_in[1];
    const float* mol_adj    = (const float*)d_in[2];
    const float* prot_adj   = (const float*)d_in[3];
    const float* Wq  = (const float*)d_in[4];
    const float* bq  = (const float*)d_in[5];
    const float* Wk  = (const float*)d_in[6];
    const float* bk  = (const float*)d_in[7];
    const float* Wv  = (const float*)d_in[8];
    const float* bv  = (const float*)d_in[9];
    const float* Wka = (const float*)d_in[10];
    const float* bka = (const float*)d_in[11];
    const float* Wva = (const float*)d_in[12];
    const float* bva = (const float*)d_in[13];
    const float* Wond = (const float*)d_in[14];
    const float* bond = (const float*)d_in[15];
    const float* Woed = (const float*)d_in[16];
    const float* boed = (const float*)d_in[17];

    // workspace: qf f32 (1MB), vf f32 (1MB), kf16 f16 (0.5MB), packed W (3x128KB)
    float*    qf     = (float*)d_ws;
    float*    vf     = qf + (size_t)kB * kN * kC;
    _Float16* kf16   = (_Float16*)(vf + (size_t)kB * kN * kC);
    _Float16* p_wva  = kf16 + (size_t)kB * kN * kC;
    _Float16* p_wka  = p_wva + (size_t)kC * kC;
    _Float16* p_woed = p_wka + (size_t)kC * kC;

    float* out  = (float*)d_out;
    float* out0 = out;
    float* out1 = out + (size_t)kB * kN * kC;
    float* out2 = out + (size_t)2 * kB * kN * kC;
    float* out3 = out2 + (size_t)kB * kN * kN * kC;

    qkv_kernel<<<dim3(kB * kN), dim3(256), 0, stream>>>(
        mol_annot, prot_annot, Wq, bq, Wk, bk, Wv, bv, qf, kf16, vf, out1);

    pack_w_kernel<<<dim3(3 * kC), dim3(256), 0, stream>>>(
        Wva, Wka, Woed, p_wva, p_wka, p_woed);

    main_kernel<<<dim3(kB * kN), dim3(512), 0, stream>>>(
        mol_adj, prot_adj, bka, bva, Wond, bond, boed,
        p_wva, p_wka, p_woed, qf, kf16, vf, out0, out2, out3);
}